// Round 3
// baseline (485.649 us; speedup 1.0000x reference)
//
#include <hip/hip_runtime.h>
#include <hip/hip_bf16.h>

// MHA: B=2 S=2048 DM=1024 H=16 DK=64.  All heavy math in bf16 MFMA, fp32 accum.
#define DM 1024
#define SL 2048
#define NH 16
#define DK 64

typedef __bf16 bf16;
typedef __bf16 bf16x8 __attribute__((ext_vector_type(8)));
typedef __bf16 bf16x4 __attribute__((ext_vector_type(4)));
typedef float f32x4 __attribute__((ext_vector_type(4)));
typedef float f32x16 __attribute__((ext_vector_type(16)));

__device__ __forceinline__ void gll16(const void* g, void* l) {
  __builtin_amdgcn_global_load_lds(
      (const __attribute__((address_space(1))) unsigned int*)g,
      (__attribute__((address_space(3))) unsigned int*)l, 16, 0, 0);
}

__device__ __forceinline__ unsigned pk2(float a, float b) {
  unsigned short lo = __builtin_bit_cast(unsigned short, (bf16)a);
  unsigned short hi = __builtin_bit_cast(unsigned short, (bf16)b);
  return (unsigned)lo | ((unsigned)hi << 16);
}

// ---------------- fp32 -> bf16 convert for q,k,v ----------------
__global__ __launch_bounds__(256) void cvt_x_kernel(
    const float* __restrict__ q, const float* __restrict__ k, const float* __restrict__ v,
    bf16* __restrict__ xq, bf16* __restrict__ xk, bf16* __restrict__ xv) {
  const float* src; bf16* dst;
  if (blockIdx.y == 0)      { src = q; dst = xq; }
  else if (blockIdx.y == 1) { src = k; dst = xk; }
  else                      { src = v; dst = xv; }
  int i = (blockIdx.x * 256 + threadIdx.x) * 8;
  f32x4 a = *(const f32x4*)(src + i);
  f32x4 b = *(const f32x4*)(src + i + 4);
  bf16x8 o;
  o[0]=(bf16)a[0]; o[1]=(bf16)a[1]; o[2]=(bf16)a[2]; o[3]=(bf16)a[3];
  o[4]=(bf16)b[0]; o[5]=(bf16)b[1]; o[6]=(bf16)b[2]; o[7]=(bf16)b[3];
  *(bf16x8*)(dst + i) = o;
}

// ------------- weight transpose + convert: T[n][k] = W[k][n] -------------
__global__ __launch_bounds__(256) void cvt_w_kernel(
    const float* __restrict__ W0, const float* __restrict__ W1,
    const float* __restrict__ W2, const float* __restrict__ W3,
    bf16* __restrict__ T0, bf16* __restrict__ T1,
    bf16* __restrict__ T2, bf16* __restrict__ T3) {
  const float* W; bf16* T;
  switch (blockIdx.y) {
    case 0:  W = W0; T = T0; break;
    case 1:  W = W1; T = T1; break;
    case 2:  W = W2; T = T2; break;
    default: W = W3; T = T3; break;
  }
  __shared__ float t[64][65];
  const int tid = threadIdx.x;
  const int tx = blockIdx.x & 15, ty = blockIdx.x >> 4;
  const int cr = tid >> 4, cc = tid & 15;
  #pragma unroll
  for (int rr = 0; rr < 4; ++rr) {
    int row = rr*16 + cr;
    f32x4 val = *(const f32x4*)(W + (ty*64 + row)*DM + tx*64 + cc*4);
    t[row][cc*4+0] = val[0]; t[row][cc*4+1] = val[1];
    t[row][cc*4+2] = val[2]; t[row][cc*4+3] = val[3];
  }
  __syncthreads();
  #pragma unroll
  for (int rr = 0; rr < 4; ++rr) {
    int nrow = rr*16 + cr;
    bf16x4 o;
    o[0] = (bf16)t[cc*4+0][nrow]; o[1] = (bf16)t[cc*4+1][nrow];
    o[2] = (bf16)t[cc*4+2][nrow]; o[3] = (bf16)t[cc*4+3][nrow];
    *(bf16x4*)(T + (tx*64 + nrow)*DM + ty*64 + cc*4) = o;
  }
}

// ---------------- 128x128 tile GEMM, BK=64, global_load_lds + XOR swizzle ----------------
// C[m][n] = sum_k A[m][k]*Bt[n][k] (+bias).
// MODE 0: fp32 row-major.  MODE 1: bf16 [bh][s][dk].  MODE 2: bf16 [bh][dk][s] (transposed).
template<int MODE>
__device__ __forceinline__ void gemm_core(
    const bf16* __restrict__ A, const bf16* __restrict__ Bt, const float* __restrict__ bias,
    bf16* __restrict__ outH, float* __restrict__ outF) {
  const int mt = blockIdx.x >> 3, nt = blockIdx.x & 7;
  const int m0 = mt*128, n0 = nt*128;
  __shared__ __attribute__((aligned(16))) bf16 As[128*64];
  __shared__ __attribute__((aligned(16))) bf16 Bs[128*64];
  const int tid = threadIdx.x, lane = tid & 63, w = tid >> 6;
  const int wm = w >> 1, wn = w & 1;
  f32x4 acc[4][4];
  #pragma unroll
  for (int x = 0; x < 4; ++x)
    #pragma unroll
    for (int y = 0; y < 4; ++y)
      #pragma unroll
      for (int e = 0; e < 4; ++e) acc[x][y][e] = 0.f;

  for (int kt = 0; kt < 16; ++kt) {
    const int k0 = kt*64;
    __syncthreads();
    #pragma unroll
    for (int i = 0; i < 4; ++i) {
      int idx = (i*4 + w)*64 + lane;
      int r = idx >> 3;
      int s = (idx & 7) ^ (r & 7);
      gll16(A  + (m0 + r)*DM + k0 + s*8, &As[(i*4 + w)*512]);
      gll16(Bt + (n0 + r)*DM + k0 + s*8, &Bs[(i*4 + w)*512]);
    }
    __syncthreads();
    bf16x8 bfr[4][2];
    #pragma unroll
    for (int ni = 0; ni < 4; ++ni) {
      int row = wn*64 + ni*16 + (lane & 15);
      #pragma unroll
      for (int c = 0; c < 2; ++c) {
        int slot = (lane >> 4) + c*4;
        bfr[ni][c] = *(const bf16x8*)&Bs[row*64 + ((slot ^ (row & 7)) << 3)];
      }
    }
    __builtin_amdgcn_s_setprio(1);
    #pragma unroll
    for (int mi = 0; mi < 4; ++mi) {
      int row = wm*64 + mi*16 + (lane & 15);
      bf16x8 a0 = *(const bf16x8*)&As[row*64 + ((((lane >> 4)    ) ^ (row & 7)) << 3)];
      bf16x8 a1 = *(const bf16x8*)&As[row*64 + ((((lane >> 4) + 4) ^ (row & 7)) << 3)];
      #pragma unroll
      for (int ni = 0; ni < 4; ++ni) {
        acc[mi][ni] = __builtin_amdgcn_mfma_f32_16x16x32_bf16(a0, bfr[ni][0], acc[mi][ni], 0, 0, 0);
        acc[mi][ni] = __builtin_amdgcn_mfma_f32_16x16x32_bf16(a1, bfr[ni][1], acc[mi][ni], 0, 0, 0);
      }
    }
    __builtin_amdgcn_s_setprio(0);
  }
  #pragma unroll
  for (int ni = 0; ni < 4; ++ni) {
    int n = n0 + wn*64 + ni*16 + (lane & 15);
    float bv = bias[n];
    #pragma unroll
    for (int mi = 0; mi < 4; ++mi) {
      int mb = m0 + wm*64 + mi*16 + ((lane >> 4) << 2);
      if (MODE == 2) {
        int bb = mb >> 11, ss = mb & 2047, hh = n >> 6, dd = n & 63;
        bf16x4 o;
        #pragma unroll
        for (int j = 0; j < 4; ++j) o[j] = (bf16)(acc[mi][ni][j] + bv);
        *(bf16x4*)&outH[(((bb << 4) + hh)*DK + dd)*SL + ss] = o;
      } else {
        #pragma unroll
        for (int j = 0; j < 4; ++j) {
          int m = mb + j;
          float val = acc[mi][ni][j] + bv;
          if (MODE == 1) {
            int bb = m >> 11, ss = m & 2047, hh = n >> 6, dd = n & 63;
            outH[(((bb << 4) + hh)*SL + ss)*DK + dd] = (bf16)val;
          } else {
            outF[m*DM + n] = val;
          }
        }
      }
    }
  }
}

__global__ __launch_bounds__(256, 2) void proj_gemm_kernel(
    const bf16* XQ, const bf16* XK, const bf16* XV,
    const bf16* WTQp, const bf16* WTKp, const bf16* WTVp,
    const float* bq, const float* bk, const float* bv,
    bf16* QHp, bf16* KHp, bf16* VTp) {
  if (blockIdx.y == 0)      gemm_core<1>(XQ, WTQp, bq, QHp, nullptr);
  else if (blockIdx.y == 1) gemm_core<1>(XK, WTKp, bk, KHp, nullptr);
  else                      gemm_core<2>(XV, WTVp, bv, VTp, nullptr);
}

__global__ __launch_bounds__(256, 2) void out_gemm_kernel(
    const bf16* CTXp, const bf16* WTOp, const float* bo, float* out) {
  gemm_core<0>(CTXp, WTOp, bo, nullptr, out);
}

// ---------------- flash attention, swapped-QK^T, 32x32x16 MFMA ----------------
// 4 waves x 32-query strips (QBLK=128), KBLK=64, 2-phase double-buffered staging,
// V pre-transposed in global (VT[bh][d][s]), in-register P redistribution, defer-max.
__global__ __launch_bounds__(256, 2) void attn_kernel(
    const bf16* __restrict__ QHp, const bf16* __restrict__ KHp,
    const bf16* __restrict__ VTp, const int* __restrict__ msk,
    bf16* __restrict__ CTXp) {
  const int bh = blockIdx.y, b = bh >> 4, h = bh & 15;
  const int q0 = blockIdx.x * 128;
  const bf16* Qp  = QHp + bh * SL * DK;
  const bf16* Kp  = KHp + bh * SL * DK;
  const bf16* Vtp = VTp + bh * SL * DK;   // [d][s]
  const int* mp = msk + b * SL;
  __shared__ __attribute__((aligned(16))) bf16 Ks[2][64*64];   // [key][d] swizzled
  __shared__ __attribute__((aligned(16))) bf16 Vts[2][64*64];  // [d][key] swizzled
  __shared__ __attribute__((aligned(16))) float mAddAll[SL];
  const int tid = threadIdx.x, lane = tid & 63, w = tid >> 6;
  const int hi = lane >> 5, l5 = lane & 31;
  const float L2E = 1.44269504f;

  // mask -> additive bias, whole sequence, once
  #pragma unroll
  for (int i = 0; i < 8; ++i) {
    int idx = i*256 + tid;
    mAddAll[idx] = (mp[idx] == 0) ? -1.0e9f : 0.0f;
  }

  // Q fragments (regs whole kernel): B-operand col = q = l5
  bf16x8 qf[4];
  {
    const bf16* qr = Qp + (q0 + w*32 + l5)*DK + hi*8;
    #pragma unroll
    for (int c = 0; c < 4; ++c) qf[c] = *(const bf16x8*)(qr + c*16);
  }
  f32x16 o0, o1;
  #pragma unroll
  for (int e = 0; e < 16; ++e) { o0[e] = 0.f; o1[e] = 0.f; }
  float m_run = -1e30f, l_run = 0.f;

  // ---- staging helper: K tile [64 keys][64 d], Vt tile [64 d][64 keys] ----
  #define STAGE(buf, kt_)                                                  \
    {                                                                      \
      const int k0s = (kt_)*64;                                            \
      _Pragma("unroll")                                                    \
      for (int i = 0; i < 2; ++i) {                                        \
        int idx = (i*4 + w)*64 + lane;                                     \
        int r = idx >> 3;                                                  \
        int s = (idx & 7) ^ (r & 7);                                       \
        gll16(Kp + (k0s + r)*DK + s*8, &Ks[buf][(i*4 + w)*512]);           \
      }                                                                    \
      _Pragma("unroll")                                                    \
      for (int i = 0; i < 2; ++i) {                                        \
        int idx = (i*4 + w)*64 + lane;                                     \
        int r = idx >> 3;                                                  \
        int s = (idx & 7) ^ (r & 7);                                       \
        gll16(Vtp + r*SL + k0s + s*8, &Vts[buf][(i*4 + w)*512]);           \
      }                                                                    \
    }

  STAGE(0, 0);
  __syncthreads();

  for (int kt = 0; kt < 32; ++kt) {
    const int cur = kt & 1;
    const int k0 = kt*64;
    if (kt < 31) STAGE(cur ^ 1, kt + 1);

    // ST[key][q] = K @ Q^T
    f32x16 s0, s1;
    #pragma unroll
    for (int e = 0; e < 16; ++e) { s0[e] = 0.f; s1[e] = 0.f; }
    __builtin_amdgcn_s_setprio(1);
    #pragma unroll
    for (int c = 0; c < 4; ++c) {
      int sl = 2*c + hi;
      int r0 = l5, r1 = 32 + l5;
      bf16x8 kf0 = *(const bf16x8*)&Ks[cur][r0*64 + ((sl ^ (r0 & 7)) << 3)];
      bf16x8 kf1 = *(const bf16x8*)&Ks[cur][r1*64 + ((sl ^ (r1 & 7)) << 3)];
      s0 = __builtin_amdgcn_mfma_f32_32x32x16_bf16(kf0, qf[c], s0, 0, 0, 0);
      s1 = __builtin_amdgcn_mfma_f32_32x32x16_bf16(kf1, qf[c], s1, 0, 0, 0);
    }
    __builtin_amdgcn_s_setprio(0);

    // scale + mask; track tile max (per q = l5, keys split across hi halves)
    float pv_[32];
    float mt = -1e30f;
    #pragma unroll
    for (int half = 0; half < 2; ++half) {
      #pragma unroll
      for (int qd = 0; qd < 4; ++qd) {
        f32x4 ma = *(const f32x4*)&mAddAll[k0 + half*32 + qd*8 + hi*4];
        #pragma unroll
        for (int j = 0; j < 4; ++j) {
          float val = (half ? s1[qd*4+j] : s0[qd*4+j]) * 0.125f + ma[j];
          pv_[half*16 + qd*4 + j] = val;
          mt = fmaxf(mt, val);
        }
      }
    }
    mt = fmaxf(mt, __shfl_xor(mt, 32));
    // defer-max: only rescale when tile max grows past threshold
    if (!__all(mt - m_run <= 8.0f)) {
      float mnew = fmaxf(m_run, mt);
      float sf = exp2f((m_run - mnew) * L2E);
      #pragma unroll
      for (int reg = 0; reg < 16; ++reg) {
        int crow = (reg & 3) + ((reg >> 2) << 3) + (hi << 2);
        float s_ = __shfl(sf, crow);
        o0[reg] *= s_; o1[reg] *= s_;
      }
      l_run *= sf;
      m_run = mnew;
    }
    float lsum = 0.f;
    #pragma unroll
    for (int t = 0; t < 32; ++t) {
      float p = exp2f((pv_[t] - m_run) * L2E);
      pv_[t] = p; lsum += p;
    }
    lsum += __shfl_xor(lsum, 32);
    l_run += lsum;

    // PV: build A-fragment pa[c] in-register (keys 16c+8*hi+0..7 at q=l5) and MFMA
    #pragma unroll
    for (int c = 0; c < 4; ++c) {
      int half_c = c >> 1;
      int qo = (2*c + hi) & 3;        // own-block qd
      int qx = (2*c + 1 - hi) & 3;    // partner-needed qd
      int io = half_c*16 + qo*4, ix = half_c*16 + qx*4;
      unsigned ow0 = pk2(pv_[io],   pv_[io+1]);
      unsigned ow1 = pk2(pv_[io+2], pv_[io+3]);
      unsigned xw0 = pk2(pv_[ix],   pv_[ix+1]);
      unsigned xw1 = pk2(pv_[ix+2], pv_[ix+3]);
      unsigned yw0 = __shfl_xor(xw0, 32);
      unsigned yw1 = __shfl_xor(xw1, 32);
      union { unsigned u[4]; bf16x8 v; } U;
      U.u[0] = hi ? yw0 : ow0;
      U.u[1] = hi ? yw1 : ow1;
      U.u[2] = hi ? ow0 : yw0;
      U.u[3] = hi ? ow1 : yw1;
      int sl = 2*c + hi;
      int r0 = l5, r1 = 32 + l5;
      bf16x8 vf0 = *(const bf16x8*)&Vts[cur][r0*64 + ((sl ^ (r0 & 7)) << 3)];
      bf16x8 vf1 = *(const bf16x8*)&Vts[cur][r1*64 + ((sl ^ (r1 & 7)) << 3)];
      __builtin_amdgcn_s_setprio(1);
      o0 = __builtin_amdgcn_mfma_f32_32x32x16_bf16(U.v, vf0, o0, 0, 0, 0);
      o1 = __builtin_amdgcn_mfma_f32_32x32x16_bf16(U.v, vf1, o1, 0, 0, 0);
      __builtin_amdgcn_s_setprio(0);
    }
    __syncthreads();
  }

  // epilogue: divide by l, write ctx[b][s][h*64+d] bf16
  float inv = 1.f / l_run;
  const int sbase = (b * SL) * DM + h * DK;
  #pragma unroll
  for (int reg = 0; reg < 16; ++reg) {
    int crow = (reg & 3) + ((reg >> 2) << 3) + (hi << 2);
    float iv = __shfl(inv, crow);
    int srow = q0 + w*32 + crow;
    CTXp[sbase + srow*DM + l5]      = (bf16)(o0[reg] * iv);
    CTXp[sbase + srow*DM + 32 + l5] = (bf16)(o1[reg] * iv);
  }
  #undef STAGE
}

extern "C" void kernel_launch(void* const* d_in, const int* in_sizes, int n_in,
                              void* d_out, int out_size, void* d_ws, size_t ws_size,
                              hipStream_t stream) {
  const float* q  = (const float*)d_in[0];
  const float* k  = (const float*)d_in[1];
  const float* v  = (const float*)d_in[2];
  const int*  msk = (const int*)d_in[3];
  const float* Wq = (const float*)d_in[4];
  const float* bq = (const float*)d_in[5];
  const float* Wk = (const float*)d_in[6];
  const float* bk = (const float*)d_in[7];
  const float* Wv = (const float*)d_in[8];
  const float* bv = (const float*)d_in[9];
  const float* Wo = (const float*)d_in[10];
  const float* bo = (const float*)d_in[11];
  char* ws = (char*)d_ws;
  bf16* XQ  = (bf16*)(ws + 0);
  bf16* XK  = (bf16*)(ws + 8388608);
  bf16* XV  = (bf16*)(ws + 16777216);
  bf16* WTQ = (bf16*)(ws + 25165824);
  bf16* WTK = (bf16*)(ws + 27262976);
  bf16* WTV = (bf16*)(ws + 29360128);
  bf16* WTO = (bf16*)(ws + 31457280);
  bf16* QHb = (bf16*)(ws + 33554432);
  bf16* KHb = (bf16*)(ws + 41943040);
  bf16* VTb = (bf16*)(ws + 50331648);   // transposed [bh][d][s]
  bf16* CTX = (bf16*)(ws + 58720256);   // total 64 MiB
  float* out = (float*)d_out;

  cvt_x_kernel<<<dim3(2048, 3), 256, 0, stream>>>(q, k, v, XQ, XK, XV);
  cvt_w_kernel<<<dim3(256, 4), 256, 0, stream>>>(Wq, Wk, Wv, Wo, WTQ, WTK, WTV, WTO);
  proj_gemm_kernel<<<dim3(256, 3), 256, 0, stream>>>(XQ, XK, XV, WTQ, WTK, WTV,
                                                     bq, bk, bv, QHb, KHb, VTb);
  attn_kernel<<<dim3(16, 32), 256, 0, stream>>>(QHb, KHb, VTb, msk, CTX);
  out_gemm_kernel<<<dim3(256, 1), 256, 0, stream>>>(CTX, WTO, bo, out);
}

// Round 4
// 269.336 us; speedup vs baseline: 1.8031x; 1.8031x over previous
//
#include <hip/hip_runtime.h>
#include <hip/hip_bf16.h>

// MHA: B=2 S=2048 DM=1024 H=16 DK=64.  All heavy math in bf16 MFMA, fp32 accum.
#define DM 1024
#define SL 2048
#define NH 16
#define DK 64

typedef __bf16 bf16;
typedef __bf16 bf16x8 __attribute__((ext_vector_type(8)));
typedef __bf16 bf16x4 __attribute__((ext_vector_type(4)));
typedef float f32x4 __attribute__((ext_vector_type(4)));
typedef float f32x16 __attribute__((ext_vector_type(16)));
typedef unsigned u32x4 __attribute__((ext_vector_type(4)));

__device__ __forceinline__ void gll16(const void* g, void* l) {
  __builtin_amdgcn_global_load_lds(
      (const __attribute__((address_space(1))) unsigned int*)g,
      (__attribute__((address_space(3))) unsigned int*)l, 16, 0, 0);
}

__device__ __forceinline__ unsigned pk2(float a, float b) {
  unsigned short lo = __builtin_bit_cast(unsigned short, (bf16)a);
  unsigned short hi = __builtin_bit_cast(unsigned short, (bf16)b);
  return (unsigned)lo | ((unsigned)hi << 16);
}

// ---------------- fp32 -> bf16 convert for q,k,v ----------------
__global__ __launch_bounds__(256) void cvt_x_kernel(
    const float* __restrict__ q, const float* __restrict__ k, const float* __restrict__ v,
    bf16* __restrict__ xq, bf16* __restrict__ xk, bf16* __restrict__ xv) {
  const float* src; bf16* dst;
  if (blockIdx.y == 0)      { src = q; dst = xq; }
  else if (blockIdx.y == 1) { src = k; dst = xk; }
  else                      { src = v; dst = xv; }
  int i = (blockIdx.x * 256 + threadIdx.x) * 8;
  f32x4 a = *(const f32x4*)(src + i);
  f32x4 b = *(const f32x4*)(src + i + 4);
  bf16x8 o;
  o[0]=(bf16)a[0]; o[1]=(bf16)a[1]; o[2]=(bf16)a[2]; o[3]=(bf16)a[3];
  o[4]=(bf16)b[0]; o[5]=(bf16)b[1]; o[6]=(bf16)b[2]; o[7]=(bf16)b[3];
  *(bf16x8*)(dst + i) = o;
}

// ------------- weight transpose + convert: T[n][k] = W[k][n] -------------
__global__ __launch_bounds__(256) void cvt_w_kernel(
    const float* __restrict__ W0, const float* __restrict__ W1,
    const float* __restrict__ W2, const float* __restrict__ W3,
    bf16* __restrict__ T0, bf16* __restrict__ T1,
    bf16* __restrict__ T2, bf16* __restrict__ T3) {
  const float* W; bf16* T;
  switch (blockIdx.y) {
    case 0:  W = W0; T = T0; break;
    case 1:  W = W1; T = T1; break;
    case 2:  W = W2; T = T2; break;
    default: W = W3; T = T3; break;
  }
  __shared__ float t[64][65];
  const int tid = threadIdx.x;
  const int tx = blockIdx.x & 15, ty = blockIdx.x >> 4;
  const int cr = tid >> 4, cc = tid & 15;
  #pragma unroll
  for (int rr = 0; rr < 4; ++rr) {
    int row = rr*16 + cr;
    f32x4 val = *(const f32x4*)(W + (ty*64 + row)*DM + tx*64 + cc*4);
    t[row][cc*4+0] = val[0]; t[row][cc*4+1] = val[1];
    t[row][cc*4+2] = val[2]; t[row][cc*4+3] = val[3];
  }
  __syncthreads();
  #pragma unroll
  for (int rr = 0; rr < 4; ++rr) {
    int nrow = rr*16 + cr;
    bf16x4 o;
    o[0] = (bf16)t[cc*4+0][nrow]; o[1] = (bf16)t[cc*4+1][nrow];
    o[2] = (bf16)t[cc*4+2][nrow]; o[3] = (bf16)t[cc*4+3][nrow];
    *(bf16x4*)(T + (tx*64 + nrow)*DM + ty*64 + cc*4) = o;
  }
}

// ---------------- 128x128 tile GEMM, BK=64, global_load_lds + XOR swizzle ----------------
// C[m][n] = sum_k A[m][k]*Bt[n][k] (+bias).
// MODE 0: fp32 row-major.  MODE 1: bf16 [bh][s][dk].  MODE 2: bf16 [bh][dk][s] (transposed).
template<int MODE>
__device__ __forceinline__ void gemm_core(
    const bf16* __restrict__ A, const bf16* __restrict__ Bt, const float* __restrict__ bias,
    bf16* __restrict__ outH, float* __restrict__ outF) {
  const int mt = blockIdx.x >> 3, nt = blockIdx.x & 7;
  const int m0 = mt*128, n0 = nt*128;
  __shared__ __attribute__((aligned(16))) bf16 As[128*64];
  __shared__ __attribute__((aligned(16))) bf16 Bs[128*64];
  const int tid = threadIdx.x, lane = tid & 63, w = tid >> 6;
  const int wm = w >> 1, wn = w & 1;
  f32x4 acc[4][4];
  #pragma unroll
  for (int x = 0; x < 4; ++x)
    #pragma unroll
    for (int y = 0; y < 4; ++y)
      #pragma unroll
      for (int e = 0; e < 4; ++e) acc[x][y][e] = 0.f;

  for (int kt = 0; kt < 16; ++kt) {
    const int k0 = kt*64;
    __syncthreads();
    #pragma unroll
    for (int i = 0; i < 4; ++i) {
      int idx = (i*4 + w)*64 + lane;
      int r = idx >> 3;
      int s = (idx & 7) ^ (r & 7);
      gll16(A  + (m0 + r)*DM + k0 + s*8, &As[(i*4 + w)*512]);
      gll16(Bt + (n0 + r)*DM + k0 + s*8, &Bs[(i*4 + w)*512]);
    }
    __syncthreads();
    bf16x8 bfr[4][2];
    #pragma unroll
    for (int ni = 0; ni < 4; ++ni) {
      int row = wn*64 + ni*16 + (lane & 15);
      #pragma unroll
      for (int c = 0; c < 2; ++c) {
        int slot = (lane >> 4) + c*4;
        bfr[ni][c] = *(const bf16x8*)&Bs[row*64 + ((slot ^ (row & 7)) << 3)];
      }
    }
    __builtin_amdgcn_s_setprio(1);
    #pragma unroll
    for (int mi = 0; mi < 4; ++mi) {
      int row = wm*64 + mi*16 + (lane & 15);
      bf16x8 a0 = *(const bf16x8*)&As[row*64 + ((((lane >> 4)    ) ^ (row & 7)) << 3)];
      bf16x8 a1 = *(const bf16x8*)&As[row*64 + ((((lane >> 4) + 4) ^ (row & 7)) << 3)];
      #pragma unroll
      for (int ni = 0; ni < 4; ++ni) {
        acc[mi][ni] = __builtin_amdgcn_mfma_f32_16x16x32_bf16(a0, bfr[ni][0], acc[mi][ni], 0, 0, 0);
        acc[mi][ni] = __builtin_amdgcn_mfma_f32_16x16x32_bf16(a1, bfr[ni][1], acc[mi][ni], 0, 0, 0);
      }
    }
    __builtin_amdgcn_s_setprio(0);
  }
  #pragma unroll
  for (int ni = 0; ni < 4; ++ni) {
    int n = n0 + wn*64 + ni*16 + (lane & 15);
    float bv = bias[n];
    #pragma unroll
    for (int mi = 0; mi < 4; ++mi) {
      int mb = m0 + wm*64 + mi*16 + ((lane >> 4) << 2);
      if (MODE == 2) {
        int bb = mb >> 11, ss = mb & 2047, hh = n >> 6, dd = n & 63;
        bf16x4 o;
        #pragma unroll
        for (int j = 0; j < 4; ++j) o[j] = (bf16)(acc[mi][ni][j] + bv);
        *(bf16x4*)&outH[(((bb << 4) + hh)*DK + dd)*SL + ss] = o;
      } else {
        #pragma unroll
        for (int j = 0; j < 4; ++j) {
          int m = mb + j;
          float val = acc[mi][ni][j] + bv;
          if (MODE == 1) {
            int bb = m >> 11, ss = m & 2047, hh = n >> 6, dd = n & 63;
            outH[(((bb << 4) + hh)*SL + ss)*DK + dd] = (bf16)val;
          } else {
            outF[m*DM + n] = val;
          }
        }
      }
    }
  }
}

__global__ __launch_bounds__(256, 2) void proj_gemm_kernel(
    const bf16* XQ, const bf16* XK, const bf16* XV,
    const bf16* WTQp, const bf16* WTKp, const bf16* WTVp,
    const float* bq, const float* bk, const float* bv,
    bf16* QHp, bf16* KHp, bf16* VTp) {
  if (blockIdx.y == 0)      gemm_core<1>(XQ, WTQp, bq, QHp, nullptr);
  else if (blockIdx.y == 1) gemm_core<1>(XK, WTKp, bk, KHp, nullptr);
  else                      gemm_core<2>(XV, WTVp, bv, VTp, nullptr);
}

__global__ __launch_bounds__(256, 2) void out_gemm_kernel(
    const bf16* CTXp, const bf16* WTOp, const float* bo, float* out) {
  gemm_core<0>(CTXp, WTOp, bo, nullptr, out);
}

// ---------------- flash attention, swapped-QK^T, 32x32x16 MFMA ----------------
// 4 waves x 32-query strips (QBLK=128), KBLK=64, 2-phase double-buffered staging,
// V pre-transposed in global (VT[bh][d][s]), in-register P redistribution (ALL
// pv_ indices compile-time — rule #20), defer-max.
__global__ __launch_bounds__(256, 2) void attn_kernel(
    const bf16* __restrict__ QHp, const bf16* __restrict__ KHp,
    const bf16* __restrict__ VTp, const int* __restrict__ msk,
    bf16* __restrict__ CTXp) {
  const int bh = blockIdx.y, b = bh >> 4, h = bh & 15;
  const int q0 = blockIdx.x * 128;
  const bf16* Qp  = QHp + bh * SL * DK;
  const bf16* Kp  = KHp + bh * SL * DK;
  const bf16* Vtp = VTp + bh * SL * DK;   // [d][s]
  const int* mp = msk + b * SL;
  __shared__ __attribute__((aligned(16))) bf16 Ks[2][64*64];   // [key][d] swizzled
  __shared__ __attribute__((aligned(16))) bf16 Vts[2][64*64];  // [d][key] swizzled
  __shared__ __attribute__((aligned(16))) float mAddAll[SL];
  const int tid = threadIdx.x, lane = tid & 63, w = tid >> 6;
  const int hi = lane >> 5, l5 = lane & 31;
  const float L2E = 1.44269504f;

  // mask -> additive bias, whole sequence, once
  #pragma unroll
  for (int i = 0; i < 8; ++i) {
    int idx = i*256 + tid;
    mAddAll[idx] = (mp[idx] == 0) ? -1.0e9f : 0.0f;
  }

  // Q fragments (regs whole kernel): B-operand col = q = l5
  bf16x8 qf[4];
  {
    const bf16* qr = Qp + (q0 + w*32 + l5)*DK + hi*8;
    #pragma unroll
    for (int c = 0; c < 4; ++c) qf[c] = *(const bf16x8*)(qr + c*16);
  }
  f32x16 o0, o1;
  #pragma unroll
  for (int e = 0; e < 16; ++e) { o0[e] = 0.f; o1[e] = 0.f; }
  float m_run = -1e30f, l_run = 0.f;

  // ---- staging helper: K tile [64 keys][64 d], Vt tile [64 d][64 keys] ----
  #define STAGE(buf, kt_)                                                  \
    {                                                                      \
      const int k0s = (kt_)*64;                                            \
      _Pragma("unroll")                                                    \
      for (int i = 0; i < 2; ++i) {                                        \
        int idx = (i*4 + w)*64 + lane;                                     \
        int r = idx >> 3;                                                  \
        int s = (idx & 7) ^ (r & 7);                                       \
        gll16(Kp + (k0s + r)*DK + s*8, &Ks[buf][(i*4 + w)*512]);           \
      }                                                                    \
      _Pragma("unroll")                                                    \
      for (int i = 0; i < 2; ++i) {                                        \
        int idx = (i*4 + w)*64 + lane;                                     \
        int r = idx >> 3;                                                  \
        int s = (idx & 7) ^ (r & 7);                                       \
        gll16(Vtp + r*SL + k0s + s*8, &Vts[buf][(i*4 + w)*512]);           \
      }                                                                    \
    }

  STAGE(0, 0);
  __syncthreads();

  for (int kt = 0; kt < 32; ++kt) {
    const int cur = kt & 1;
    const int k0 = kt*64;
    if (kt < 31) STAGE(cur ^ 1, kt + 1);

    // ST[key][q] = K @ Q^T
    f32x16 s0, s1;
    #pragma unroll
    for (int e = 0; e < 16; ++e) { s0[e] = 0.f; s1[e] = 0.f; }
    __builtin_amdgcn_s_setprio(1);
    #pragma unroll
    for (int c = 0; c < 4; ++c) {
      int sl = 2*c + hi;
      int r0 = l5, r1 = 32 + l5;
      bf16x8 kf0 = *(const bf16x8*)&Ks[cur][r0*64 + ((sl ^ (r0 & 7)) << 3)];
      bf16x8 kf1 = *(const bf16x8*)&Ks[cur][r1*64 + ((sl ^ (r1 & 7)) << 3)];
      s0 = __builtin_amdgcn_mfma_f32_32x32x16_bf16(kf0, qf[c], s0, 0, 0, 0);
      s1 = __builtin_amdgcn_mfma_f32_32x32x16_bf16(kf1, qf[c], s1, 0, 0, 0);
    }
    __builtin_amdgcn_s_setprio(0);

    // scale + mask; track tile max (per q = l5, keys split across hi halves)
    float pv_[32];
    float mt = -1e30f;
    #pragma unroll
    for (int half = 0; half < 2; ++half) {
      #pragma unroll
      for (int qd = 0; qd < 4; ++qd) {
        f32x4 ma = *(const f32x4*)&mAddAll[k0 + half*32 + qd*8 + hi*4];
        #pragma unroll
        for (int j = 0; j < 4; ++j) {
          float val = (half ? s1[qd*4+j] : s0[qd*4+j]) * 0.125f + ma[j];
          pv_[half*16 + qd*4 + j] = val;
          mt = fmaxf(mt, val);
        }
      }
    }
    mt = fmaxf(mt, __shfl_xor(mt, 32));
    // defer-max: only rescale when tile max grows past threshold
    if (!__all(mt - m_run <= 8.0f)) {
      float mnew = fmaxf(m_run, mt);
      float sf = exp2f((m_run - mnew) * L2E);
      #pragma unroll
      for (int reg = 0; reg < 16; ++reg) {
        int crow = (reg & 3) + ((reg >> 2) << 3) + (hi << 2);
        float s_ = __shfl(sf, crow);
        o0[reg] *= s_; o1[reg] *= s_;
      }
      l_run *= sf;
      m_run = mnew;
    }
    float lsum = 0.f;
    #pragma unroll
    for (int t = 0; t < 32; ++t) {
      float p = exp2f((pv_[t] - m_run) * L2E);
      pv_[t] = p; lsum += p;
    }
    lsum += __shfl_xor(lsum, 32);
    l_run += lsum;

    // PV: build A-fragment in-register.  Both candidate sub-blocks use STATIC
    // pv_ indices; hi only selects between REGISTERS (cndmask) — no scratch.
    #pragma unroll
    for (int c = 0; c < 4; ++c) {
      const int half_c = c >> 1;
      const int iA = half_c*16 + (((2*c)    ) & 3)*4;   // static
      const int iB = half_c*16 + (((2*c) + 1) & 3)*4;   // static
      unsigned wA0 = pk2(pv_[iA],   pv_[iA+1]);
      unsigned wA1 = pk2(pv_[iA+2], pv_[iA+3]);
      unsigned wB0 = pk2(pv_[iB],   pv_[iB+1]);
      unsigned wB1 = pk2(pv_[iB+2], pv_[iB+3]);
      unsigned ow0 = hi ? wB0 : wA0, ow1 = hi ? wB1 : wA1;   // own block
      unsigned xw0 = hi ? wA0 : wB0, xw1 = hi ? wA1 : wB1;   // partner's block
      unsigned yw0 = __shfl_xor(xw0, 32);
      unsigned yw1 = __shfl_xor(xw1, 32);
      u32x4 uu;
      uu[0] = hi ? yw0 : ow0;
      uu[1] = hi ? yw1 : ow1;
      uu[2] = hi ? ow0 : yw0;
      uu[3] = hi ? ow1 : yw1;
      bf16x8 pa = __builtin_bit_cast(bf16x8, uu);
      int sl = 2*c + hi;
      int r0 = l5, r1 = 32 + l5;
      bf16x8 vf0 = *(const bf16x8*)&Vts[cur][r0*64 + ((sl ^ (r0 & 7)) << 3)];
      bf16x8 vf1 = *(const bf16x8*)&Vts[cur][r1*64 + ((sl ^ (r1 & 7)) << 3)];
      __builtin_amdgcn_s_setprio(1);
      o0 = __builtin_amdgcn_mfma_f32_32x32x16_bf16(pa, vf0, o0, 0, 0, 0);
      o1 = __builtin_amdgcn_mfma_f32_32x32x16_bf16(pa, vf1, o1, 0, 0, 0);
      __builtin_amdgcn_s_setprio(0);
    }
    __syncthreads();
  }

  // epilogue: divide by l, write ctx[b][s][h*64+d] bf16
  float inv = 1.f / l_run;
  const int sbase = (b * SL) * DM + h * DK;
  #pragma unroll
  for (int reg = 0; reg < 16; ++reg) {
    int crow = (reg & 3) + ((reg >> 2) << 3) + (hi << 2);
    float iv = __shfl(inv, crow);
    int srow = q0 + w*32 + crow;
    CTXp[sbase + srow*DM + l5]      = (bf16)(o0[reg] * iv);
    CTXp[sbase + srow*DM + 32 + l5] = (bf16)(o1[reg] * iv);
  }
  #undef STAGE
}

extern "C" void kernel_launch(void* const* d_in, const int* in_sizes, int n_in,
                              void* d_out, int out_size, void* d_ws, size_t ws_size,
                              hipStream_t stream) {
  const float* q  = (const float*)d_in[0];
  const float* k  = (const float*)d_in[1];
  const float* v  = (const float*)d_in[2];
  const int*  msk = (const int*)d_in[3];
  const float* Wq = (const float*)d_in[4];
  const float* bq = (const float*)d_in[5];
  const float* Wk = (const float*)d_in[6];
  const float* bk = (const float*)d_in[7];
  const float* Wv = (const float*)d_in[8];
  const float* bv = (const float*)d_in[9];
  const float* Wo = (const float*)d_in[10];
  const float* bo = (const float*)d_in[11];
  char* ws = (char*)d_ws;
  bf16* XQ  = (bf16*)(ws + 0);
  bf16* XK  = (bf16*)(ws + 8388608);
  bf16* XV  = (bf16*)(ws + 16777216);
  bf16* WTQ = (bf16*)(ws + 25165824);
  bf16* WTK = (bf16*)(ws + 27262976);
  bf16* WTV = (bf16*)(ws + 29360128);
  bf16* WTO = (bf16*)(ws + 31457280);
  bf16* QHb = (bf16*)(ws + 33554432);
  bf16* KHb = (bf16*)(ws + 41943040);
  bf16* VTb = (bf16*)(ws + 50331648);   // transposed [bh][d][s]
  bf16* CTX = (bf16*)(ws + 58720256);   // total 64 MiB
  float* out = (float*)d_out;

  cvt_x_kernel<<<dim3(2048, 3), 256, 0, stream>>>(q, k, v, XQ, XK, XV);
  cvt_w_kernel<<<dim3(256, 4), 256, 0, stream>>>(Wq, Wk, Wv, Wo, WTQ, WTK, WTV, WTO);
  proj_gemm_kernel<<<dim3(256, 3), 256, 0, stream>>>(XQ, XK, XV, WTQ, WTK, WTV,
                                                     bq, bk, bv, QHb, KHb, VTb);
  attn_kernel<<<dim3(16, 32), 256, 0, stream>>>(QHb, KHb, VTb, msk, CTX);
  out_gemm_kernel<<<dim3(256, 1), 256, 0, stream>>>(CTX, WTO, bo, out);
}

// Round 5
// 258.433 us; speedup vs baseline: 1.8792x; 1.0422x over previous
//
#include <hip/hip_runtime.h>
#include <hip/hip_bf16.h>

// MHA: B=2 S=2048 DM=1024 H=16 DK=64.  All heavy math in bf16 MFMA, fp32 accum.
#define DM 1024
#define SL 2048
#define NH 16
#define DK 64

typedef __bf16 bf16;
typedef __bf16 bf16x8 __attribute__((ext_vector_type(8)));
typedef __bf16 bf16x4 __attribute__((ext_vector_type(4)));
typedef float f32x4 __attribute__((ext_vector_type(4)));
typedef float f32x16 __attribute__((ext_vector_type(16)));
typedef unsigned u32x4 __attribute__((ext_vector_type(4)));

__device__ __forceinline__ void gll16(const void* g, void* l) {
  __builtin_amdgcn_global_load_lds(
      (const __attribute__((address_space(1))) unsigned int*)g,
      (__attribute__((address_space(3))) unsigned int*)l, 16, 0, 0);
}

__device__ __forceinline__ unsigned pk2(float a, float b) {
  unsigned short lo = __builtin_bit_cast(unsigned short, (bf16)a);
  unsigned short hi = __builtin_bit_cast(unsigned short, (bf16)b);
  return (unsigned)lo | ((unsigned)hi << 16);
}

// ---------------- fp32 -> bf16 convert for q,k,v ----------------
__global__ __launch_bounds__(256) void cvt_x_kernel(
    const float* __restrict__ q, const float* __restrict__ k, const float* __restrict__ v,
    bf16* __restrict__ xq, bf16* __restrict__ xk, bf16* __restrict__ xv) {
  const float* src; bf16* dst;
  if (blockIdx.y == 0)      { src = q; dst = xq; }
  else if (blockIdx.y == 1) { src = k; dst = xk; }
  else                      { src = v; dst = xv; }
  int i = (blockIdx.x * 256 + threadIdx.x) * 8;
  f32x4 a = *(const f32x4*)(src + i);
  f32x4 b = *(const f32x4*)(src + i + 4);
  bf16x8 o;
  o[0]=(bf16)a[0]; o[1]=(bf16)a[1]; o[2]=(bf16)a[2]; o[3]=(bf16)a[3];
  o[4]=(bf16)b[0]; o[5]=(bf16)b[1]; o[6]=(bf16)b[2]; o[7]=(bf16)b[3];
  *(bf16x8*)(dst + i) = o;
}

// ------------- weight transpose + convert: T[n][k] = W[k][n] -------------
__global__ __launch_bounds__(256) void cvt_w_kernel(
    const float* __restrict__ W0, const float* __restrict__ W1,
    const float* __restrict__ W2, const float* __restrict__ W3,
    bf16* __restrict__ T0, bf16* __restrict__ T1,
    bf16* __restrict__ T2, bf16* __restrict__ T3) {
  const float* W; bf16* T;
  switch (blockIdx.y) {
    case 0:  W = W0; T = T0; break;
    case 1:  W = W1; T = T1; break;
    case 2:  W = W2; T = T2; break;
    default: W = W3; T = T3; break;
  }
  __shared__ float t[64][65];
  const int tid = threadIdx.x;
  const int tx = blockIdx.x & 15, ty = blockIdx.x >> 4;
  const int cr = tid >> 4, cc = tid & 15;
  #pragma unroll
  for (int rr = 0; rr < 4; ++rr) {
    int row = rr*16 + cr;
    f32x4 val = *(const f32x4*)(W + (ty*64 + row)*DM + tx*64 + cc*4);
    t[row][cc*4+0] = val[0]; t[row][cc*4+1] = val[1];
    t[row][cc*4+2] = val[2]; t[row][cc*4+3] = val[3];
  }
  __syncthreads();
  #pragma unroll
  for (int rr = 0; rr < 4; ++rr) {
    int nrow = rr*16 + cr;
    bf16x4 o;
    o[0] = (bf16)t[cc*4+0][nrow]; o[1] = (bf16)t[cc*4+1][nrow];
    o[2] = (bf16)t[cc*4+2][nrow]; o[3] = (bf16)t[cc*4+3][nrow];
    *(bf16x4*)(T + (tx*64 + nrow)*DM + ty*64 + cc*4) = o;
  }
}

// ---------------- mask -> additive bias (L2E-scaled), 2x2048 floats -------
__global__ __launch_bounds__(256) void maskcvt_kernel(
    const int* __restrict__ msk, float* __restrict__ mBias) {
  int i = (blockIdx.x * 256 + threadIdx.x) * 4;   // 4 blocks cover 2*2048
  int4 m4 = *(const int4*)(msk + i);
  f32x4 o;
  o[0] = (m4.x == 0) ? -1.4426950e9f : 0.f;
  o[1] = (m4.y == 0) ? -1.4426950e9f : 0.f;
  o[2] = (m4.z == 0) ? -1.4426950e9f : 0.f;
  o[3] = (m4.w == 0) ? -1.4426950e9f : 0.f;
  *(f32x4*)(mBias + i) = o;
}

// ---------------- 64x128 tile GEMM, BK=64, global_load_lds + XOR swizzle ----------------
// C[m][n] = sum_k A[m][k]*Bt[n][k] (+bias).  4 waves in 2x2 (wave tile 32x64).
// MODE 0: fp32 row-major.  MODE 1: bf16 [bh][s][dk].  MODE 2: bf16 [bh][dk][s] (transposed).
template<int MODE>
__device__ __forceinline__ void gemm_core(
    const bf16* __restrict__ A, const bf16* __restrict__ Bt, const float* __restrict__ bias,
    bf16* __restrict__ outH, float* __restrict__ outF) {
  // XCD-aware bijective swizzle of 512 blocks: xcd gets 64 consecutive swz ids
  const int bid = blockIdx.x;
  const int swz = (bid & 7) * 64 + (bid >> 3);
  const int mt = swz >> 3, nt = swz & 7;
  const int m0 = mt*64, n0 = nt*128;
  __shared__ __attribute__((aligned(16))) bf16 As[64*64];
  __shared__ __attribute__((aligned(16))) bf16 Bs[128*64];
  const int tid = threadIdx.x, lane = tid & 63, w = tid >> 6;
  const int wm = w >> 1, wn = w & 1;
  f32x4 acc[2][4];
  #pragma unroll
  for (int x = 0; x < 2; ++x)
    #pragma unroll
    for (int y = 0; y < 4; ++y)
      #pragma unroll
      for (int e = 0; e < 4; ++e) acc[x][y][e] = 0.f;

  for (int kt = 0; kt < 16; ++kt) {
    const int k0 = kt*64;
    __syncthreads();
    #pragma unroll
    for (int i = 0; i < 2; ++i) {          // A: 512 slots
      int idx = (i*4 + w)*64 + lane;
      int r = idx >> 3;
      int s = (idx & 7) ^ (r & 7);
      gll16(A + (m0 + r)*DM + k0 + s*8, &As[(i*4 + w)*512]);
    }
    #pragma unroll
    for (int i = 0; i < 4; ++i) {          // B: 1024 slots
      int idx = (i*4 + w)*64 + lane;
      int r = idx >> 3;
      int s = (idx & 7) ^ (r & 7);
      gll16(Bt + (n0 + r)*DM + k0 + s*8, &Bs[(i*4 + w)*512]);
    }
    __syncthreads();
    bf16x8 bfr[4][2];
    #pragma unroll
    for (int ni = 0; ni < 4; ++ni) {
      int row = wn*64 + ni*16 + (lane & 15);
      #pragma unroll
      for (int c = 0; c < 2; ++c) {
        int slot = (lane >> 4) + c*4;
        bfr[ni][c] = *(const bf16x8*)&Bs[row*64 + ((slot ^ (row & 7)) << 3)];
      }
    }
    __builtin_amdgcn_s_setprio(1);
    #pragma unroll
    for (int mi = 0; mi < 2; ++mi) {
      int row = wm*32 + mi*16 + (lane & 15);
      bf16x8 a0 = *(const bf16x8*)&As[row*64 + ((((lane >> 4)    ) ^ (row & 7)) << 3)];
      bf16x8 a1 = *(const bf16x8*)&As[row*64 + ((((lane >> 4) + 4) ^ (row & 7)) << 3)];
      #pragma unroll
      for (int ni = 0; ni < 4; ++ni) {
        acc[mi][ni] = __builtin_amdgcn_mfma_f32_16x16x32_bf16(a0, bfr[ni][0], acc[mi][ni], 0, 0, 0);
        acc[mi][ni] = __builtin_amdgcn_mfma_f32_16x16x32_bf16(a1, bfr[ni][1], acc[mi][ni], 0, 0, 0);
      }
    }
    __builtin_amdgcn_s_setprio(0);
  }
  #pragma unroll
  for (int ni = 0; ni < 4; ++ni) {
    int n = n0 + wn*64 + ni*16 + (lane & 15);
    float bv = bias[n];
    #pragma unroll
    for (int mi = 0; mi < 2; ++mi) {
      int mb = m0 + wm*32 + mi*16 + ((lane >> 4) << 2);
      if (MODE == 2) {
        int bb = mb >> 11, ss = mb & 2047, hh = n >> 6, dd = n & 63;
        bf16x4 o;
        #pragma unroll
        for (int j = 0; j < 4; ++j) o[j] = (bf16)(acc[mi][ni][j] + bv);
        *(bf16x4*)&outH[(((bb << 4) + hh)*DK + dd)*SL + ss] = o;
      } else {
        #pragma unroll
        for (int j = 0; j < 4; ++j) {
          int m = mb + j;
          float val = acc[mi][ni][j] + bv;
          if (MODE == 1) {
            int bb = m >> 11, ss = m & 2047, hh = n >> 6, dd = n & 63;
            outH[(((bb << 4) + hh)*SL + ss)*DK + dd] = (bf16)val;
          } else {
            outF[m*DM + n] = val;
          }
        }
      }
    }
  }
}

__global__ __launch_bounds__(256, 4) void proj_gemm_kernel(
    const bf16* XQ, const bf16* XK, const bf16* XV,
    const bf16* WTQp, const bf16* WTKp, const bf16* WTVp,
    const float* bq, const float* bk, const float* bv,
    bf16* QHp, bf16* KHp, bf16* VTp) {
  if (blockIdx.y == 0)      gemm_core<1>(XQ, WTQp, bq, QHp, nullptr);
  else if (blockIdx.y == 1) gemm_core<1>(XK, WTKp, bk, KHp, nullptr);
  else                      gemm_core<2>(XV, WTVp, bv, VTp, nullptr);
}

__global__ __launch_bounds__(256, 4) void out_gemm_kernel(
    const bf16* CTXp, const bf16* WTOp, const float* bo, float* out) {
  gemm_core<0>(CTXp, WTOp, bo, nullptr, out);
}

// ---------------- flash attention, swapped-QK^T, 32x32x16 MFMA ----------------
// 4 waves x 32-query strips (QBLK=128), KBLK=64, 2-phase double-buffered staging,
// V pre-transposed (VT[bh][d][s]), in-register P redistribution (static indices),
// defer-max, L2E-folded scores, reg-resident mask bias, XCD-bh clustering.
__global__ __launch_bounds__(256, 2) void attn_kernel(
    const bf16* __restrict__ QHp, const bf16* __restrict__ KHp,
    const bf16* __restrict__ VTp, const float* __restrict__ mBias,
    bf16* __restrict__ CTXp) {
  // bijective XCD swizzle over 512 blocks: xcd d&7 owns bh in [4*xcd, 4*xcd+4)
  const int d = blockIdx.x;
  const int xcd = d & 7, rr = d >> 3;
  const int bh = xcd*4 + (rr >> 4);
  const int qt = rr & 15;
  const int b = bh >> 4, h = bh & 15;
  const int q0 = qt * 128;
  const bf16* Qp  = QHp + bh * SL * DK;
  const bf16* Kp  = KHp + bh * SL * DK;
  const bf16* Vtp = VTp + bh * SL * DK;   // [d][s]
  const float* mb_ = mBias + b * SL;
  __shared__ __attribute__((aligned(16))) bf16 Ks[2][64*64];   // [key][d] swizzled
  __shared__ __attribute__((aligned(16))) bf16 Vts[2][64*64];  // [d][key] swizzled
  const int tid = threadIdx.x, lane = tid & 63, w = tid >> 6;
  const int hi = lane >> 5, l5 = lane & 31;
  const float SCL2E = 0.18033688f;   // 0.125 * log2(e)

  // Q fragments (regs whole kernel): B-operand col = q = l5
  bf16x8 qf[4];
  {
    const bf16* qr = Qp + (q0 + w*32 + l5)*DK + hi*8;
    #pragma unroll
    for (int c = 0; c < 4; ++c) qf[c] = *(const bf16x8*)(qr + c*16);
  }
  f32x16 o0, o1;
  #pragma unroll
  for (int e = 0; e < 16; ++e) { o0[e] = 0.f; o1[e] = 0.f; }
  float m_run = -1e30f, l_run = 0.f;   // m_run in log2 units

  #define STAGE(buf, kt_)                                                  \
    {                                                                      \
      const int k0s = (kt_)*64;                                            \
      _Pragma("unroll")                                                    \
      for (int i = 0; i < 2; ++i) {                                        \
        int idx = (i*4 + w)*64 + lane;                                     \
        int r = idx >> 3;                                                  \
        int s = (idx & 7) ^ (r & 7);                                       \
        gll16(Kp + (k0s + r)*DK + s*8, &Ks[buf][(i*4 + w)*512]);           \
      }                                                                    \
      _Pragma("unroll")                                                    \
      for (int i = 0; i < 2; ++i) {                                        \
        int idx = (i*4 + w)*64 + lane;                                     \
        int r = idx >> 3;                                                  \
        int s = (idx & 7) ^ (r & 7);                                       \
        gll16(Vtp + r*SL + k0s + s*8, &Vts[buf][(i*4 + w)*512]);           \
      }                                                                    \
    }

  STAGE(0, 0);
  __syncthreads();

  for (int kt = 0; kt < 32; ++kt) {
    const int cur = kt & 1;
    const int k0 = kt*64;

    // mask bias -> regs FIRST (so its vmcnt wait doesn't drain the prefetch)
    f32x4 mreg[2][4];
    #pragma unroll
    for (int half = 0; half < 2; ++half)
      #pragma unroll
      for (int qd = 0; qd < 4; ++qd)
        mreg[half][qd] = *(const f32x4*)&mb_[k0 + half*32 + qd*8 + hi*4];

    if (kt < 31) STAGE(cur ^ 1, kt + 1);

    // ST[key][q] = K @ Q^T
    f32x16 s0, s1;
    #pragma unroll
    for (int e = 0; e < 16; ++e) { s0[e] = 0.f; s1[e] = 0.f; }
    __builtin_amdgcn_s_setprio(1);
    #pragma unroll
    for (int c = 0; c < 4; ++c) {
      int sl = 2*c + hi;
      int r0 = l5, r1 = 32 + l5;
      bf16x8 kf0 = *(const bf16x8*)&Ks[cur][r0*64 + ((sl ^ (r0 & 7)) << 3)];
      bf16x8 kf1 = *(const bf16x8*)&Ks[cur][r1*64 + ((sl ^ (r1 & 7)) << 3)];
      s0 = __builtin_amdgcn_mfma_f32_32x32x16_bf16(kf0, qf[c], s0, 0, 0, 0);
      s1 = __builtin_amdgcn_mfma_f32_32x32x16_bf16(kf1, qf[c], s1, 0, 0, 0);
    }
    __builtin_amdgcn_s_setprio(0);

    // scale+mask in log2 units; tree-reduced max
    float pv_[32];
    float mtv0 = -1e30f, mtv1 = -1e30f, mtv2 = -1e30f, mtv3 = -1e30f;
    #pragma unroll
    for (int half = 0; half < 2; ++half) {
      #pragma unroll
      for (int qd = 0; qd < 4; ++qd) {
        f32x4 ma = mreg[half][qd];
        #pragma unroll
        for (int j = 0; j < 4; ++j) {
          float val = (half ? s1[qd*4+j] : s0[qd*4+j]) * SCL2E + ma[j];
          pv_[half*16 + qd*4 + j] = val;
          if (j == 0) mtv0 = fmaxf(mtv0, val);
          else if (j == 1) mtv1 = fmaxf(mtv1, val);
          else if (j == 2) mtv2 = fmaxf(mtv2, val);
          else mtv3 = fmaxf(mtv3, val);
        }
      }
    }
    float mt = fmaxf(fmaxf(mtv0, mtv1), fmaxf(mtv2, mtv3));
    mt = fmaxf(mt, __shfl_xor(mt, 32));
    // defer-max (threshold 8 nats ~ 11.54 log2-units)
    if (!__all(mt - m_run <= 11.5f)) {
      float mnew = fmaxf(m_run, mt);
      float sf = exp2f(m_run - mnew);
      #pragma unroll
      for (int reg = 0; reg < 16; ++reg) {
        int crow = (reg & 3) + ((reg >> 2) << 3) + (hi << 2);
        float s_ = __shfl(sf, crow);
        o0[reg] *= s_; o1[reg] *= s_;
      }
      l_run *= sf;
      m_run = mnew;
    }
    float ls0 = 0.f, ls1 = 0.f, ls2 = 0.f, ls3 = 0.f;
    #pragma unroll
    for (int t = 0; t < 32; ++t) {
      float p = exp2f(pv_[t] - m_run);
      pv_[t] = p;
      if ((t & 3) == 0) ls0 += p;
      else if ((t & 3) == 1) ls1 += p;
      else if ((t & 3) == 2) ls2 += p;
      else ls3 += p;
    }
    float lsum = (ls0 + ls1) + (ls2 + ls3);
    lsum += __shfl_xor(lsum, 32);
    l_run += lsum;

    // PV A-fragment in-register; all pv_ indices static, hi selects registers
    #pragma unroll
    for (int c = 0; c < 4; ++c) {
      const int half_c = c >> 1;
      const int iA = half_c*16 + (((2*c)    ) & 3)*4;
      const int iB = half_c*16 + (((2*c) + 1) & 3)*4;
      unsigned wA0 = pk2(pv_[iA],   pv_[iA+1]);
      unsigned wA1 = pk2(pv_[iA+2], pv_[iA+3]);
      unsigned wB0 = pk2(pv_[iB],   pv_[iB+1]);
      unsigned wB1 = pk2(pv_[iB+2], pv_[iB+3]);
      unsigned ow0 = hi ? wB0 : wA0, ow1 = hi ? wB1 : wA1;
      unsigned xw0 = hi ? wA0 : wB0, xw1 = hi ? wA1 : wB1;
      unsigned yw0 = __shfl_xor(xw0, 32);
      unsigned yw1 = __shfl_xor(xw1, 32);
      u32x4 uu;
      uu[0] = hi ? yw0 : ow0;
      uu[1] = hi ? yw1 : ow1;
      uu[2] = hi ? ow0 : yw0;
      uu[3] = hi ? ow1 : yw1;
      bf16x8 pa = __builtin_bit_cast(bf16x8, uu);
      int sl = 2*c + hi;
      int r0 = l5, r1 = 32 + l5;
      bf16x8 vf0 = *(const bf16x8*)&Vts[cur][r0*64 + ((sl ^ (r0 & 7)) << 3)];
      bf16x8 vf1 = *(const bf16x8*)&Vts[cur][r1*64 + ((sl ^ (r1 & 7)) << 3)];
      __builtin_amdgcn_s_setprio(1);
      o0 = __builtin_amdgcn_mfma_f32_32x32x16_bf16(pa, vf0, o0, 0, 0, 0);
      o1 = __builtin_amdgcn_mfma_f32_32x32x16_bf16(pa, vf1, o1, 0, 0, 0);
      __builtin_amdgcn_s_setprio(0);
    }
    __syncthreads();
  }

  // epilogue
  float inv = 1.f / l_run;
  const int sbase = (b * SL) * DM + h * DK;
  #pragma unroll
  for (int reg = 0; reg < 16; ++reg) {
    int crow = (reg & 3) + ((reg >> 2) << 3) + (hi << 2);
    float iv = __shfl(inv, crow);
    int srow = q0 + w*32 + crow;
    CTXp[sbase + srow*DM + l5]      = (bf16)(o0[reg] * iv);
    CTXp[sbase + srow*DM + 32 + l5] = (bf16)(o1[reg] * iv);
  }
  #undef STAGE
}

extern "C" void kernel_launch(void* const* d_in, const int* in_sizes, int n_in,
                              void* d_out, int out_size, void* d_ws, size_t ws_size,
                              hipStream_t stream) {
  const float* q  = (const float*)d_in[0];
  const float* k  = (const float*)d_in[1];
  const float* v  = (const float*)d_in[2];
  const int*  msk = (const int*)d_in[3];
  const float* Wq = (const float*)d_in[4];
  const float* bq = (const float*)d_in[5];
  const float* Wk = (const float*)d_in[6];
  const float* bk = (const float*)d_in[7];
  const float* Wv = (const float*)d_in[8];
  const float* bv = (const float*)d_in[9];
  const float* Wo = (const float*)d_in[10];
  const float* bo = (const float*)d_in[11];
  char* ws = (char*)d_ws;
  bf16* XQ  = (bf16*)(ws + 0);
  bf16* XK  = (bf16*)(ws + 8388608);
  bf16* XV  = (bf16*)(ws + 16777216);
  bf16* WTQ = (bf16*)(ws + 25165824);
  bf16* WTK = (bf16*)(ws + 27262976);
  bf16* WTV = (bf16*)(ws + 29360128);
  bf16* WTO = (bf16*)(ws + 31457280);
  bf16* QHb = (bf16*)(ws + 33554432);
  bf16* KHb = (bf16*)(ws + 41943040);
  bf16* VTb = (bf16*)(ws + 50331648);   // transposed [bh][d][s]
  bf16* CTX = (bf16*)(ws + 58720256);   // total 64 MiB
  float* mBias = (float*)(ws + 0);      // reuses XQ space (dead after proj_gemm)
  float* out = (float*)d_out;

  cvt_x_kernel<<<dim3(2048, 3), 256, 0, stream>>>(q, k, v, XQ, XK, XV);
  cvt_w_kernel<<<dim3(256, 4), 256, 0, stream>>>(Wq, Wk, Wv, Wo, WTQ, WTK, WTV, WTO);
  proj_gemm_kernel<<<dim3(512, 3), 256, 0, stream>>>(XQ, XK, XV, WTQ, WTK, WTV,
                                                     bq, bk, bv, QHb, KHb, VTb);
  maskcvt_kernel<<<dim3(4), 256, 0, stream>>>(msk, mBias);
  attn_kernel<<<dim3(512), 256, 0, stream>>>(QHb, KHb, VTb, mBias, CTX);
  out_gemm_kernel<<<dim3(512), 256, 0, stream>>>(CTX, WTO, bo, out);
}